// Round 1
// baseline (1062.726 us; speedup 1.0000x reference)
//
#include <hip/hip_runtime.h>
#include <math.h>

#define BB 16
#define PP (768*768)        // 589824
#define NBINS 16384
#define KALL 176947         // int(P * 0.3)

#define LOV_LO (-17.0f)
#define LOV_RANGE 34.0f
#define NEG_RANGE 17.0f

struct Acc {
  float pos_sum, pos_w, tpx, fnx, fpx, bce0;
  unsigned max_bce_bits, sum_t, n_tis, pad0;
  float lov_i, ft_i, ohem_i; unsigned posb;
  unsigned pad1, pad2;      // 64 bytes total
};

__device__ inline float wred_sum(float v) {
  #pragma unroll
  for (int o = 32; o > 0; o >>= 1) v += __shfl_down(v, o, 64);
  return v;
}
__device__ inline float wred_max(float v) {
  #pragma unroll
  for (int o = 32; o > 0; o >>= 1) v = fmaxf(v, __shfl_down(v, o, 64));
  return v;
}
__device__ inline unsigned wred_sumu(unsigned v) {
  #pragma unroll
  for (int o = 32; o > 0; o >>= 1) v += __shfl_down(v, o, 64);
  return v;
}

// ---------------- K1: fused elementwise pass ----------------
__global__ __launch_bounds__(256) void k_main(const float* __restrict__ logits,
                                              const int* __restrict__ targets,
                                              const float* __restrict__ mask,
                                              Acc* __restrict__ acc,
                                              unsigned long long* __restrict__ lov_hist,
                                              unsigned* __restrict__ neg_hist)
{
  const int b = blockIdx.y;
  const float4* l4 = (const float4*)(logits + (size_t)b * PP);
  const int4*   t4 = (const int4*)(targets + (size_t)b * PP);
  const float4* m4 = (const float4*)(mask + (size_t)b * PP);
  unsigned long long* lh = lov_hist + (size_t)b * NBINS;
  unsigned*           nh = neg_hist + (size_t)b * NBINS;

  const float lov_scale = (float)NBINS / LOV_RANGE;
  const float neg_scale = (float)NBINS / NEG_RANGE;

  float pos_sum = 0.f, pos_w = 0.f, tpa = 0.f, fna = 0.f, fpa = 0.f, mx = 0.f;
  unsigned sum_t = 0, n_tis = 0;

  const int stride = blockDim.x * gridDim.x;
  const int tid = blockIdx.x * blockDim.x + threadIdx.x;
  const int n4 = PP / 4;

  for (int i = tid; i < n4; i += stride) {
    float4 lv = l4[i]; int4 tv = t4[i]; float4 mv = m4[i];
    float ls[4] = {lv.x, lv.y, lv.z, lv.w};
    int   ts[4] = {tv.x, tv.y, tv.z, tv.w};
    float ms[4] = {mv.x, mv.y, mv.z, mv.w};
    #pragma unroll
    for (int c = 0; c < 4; ++c) {
      float l = ls[c]; int ti = ts[c]; float tf = (float)ti; float m = ms[c];
      float ex = expf(-fabsf(l));          // shared between softplus & sigmoid
      float lg = log1pf(ex);
      float sp = fmaxf(l, 0.f) + lg;       // softplus(l) = max(l,0)+log1p(exp(-|l|))
      float loss = (sp - l * tf) * m;      // bce * mask
      float posw = tf * m;
      pos_sum += loss * posw;
      pos_w   += posw;
      float pr = ((l >= 0.f) ? 1.f : ex) / (1.f + ex);   // sigmoid(l)
      tpa += pr * tf;
      fna += (1.f - pr) * tf;
      fpa += pr * (1.f - tf);
      sum_t += (unsigned)ti;
      bool tis = (m == 1.0f);
      if (tis) { n_tis++; mx = fmaxf(mx, loss); }
      // lovasz error histogram (count | pos<<32)
      float e = 1.f - l * (2.f * tf - 1.f);
      int bin = (int)((e - LOV_LO) * lov_scale);
      bin = bin < 0 ? 0 : (bin > NBINS - 1 ? NBINS - 1 : bin);
      atomicAdd(lh + bin, 1ull | ((unsigned long long)(unsigned)ti << 32));
      // negative-bce histogram (for OHEM top-k; rarely needed but correct)
      if (ti == 0 && tis) {
        int nb = (int)(loss * neg_scale);
        nb = nb < 0 ? 0 : (nb > NBINS - 1 ? NBINS - 1 : nb);
        atomicAdd(nh + nb, 1u);
      }
      if (tid == 0 && i == 0 && c == 0) acc[b].bce0 = loss;  // loss_i[0] fallback
    }
  }

  pos_sum = wred_sum(pos_sum); pos_w = wred_sum(pos_w);
  tpa = wred_sum(tpa); fna = wred_sum(fna); fpa = wred_sum(fpa);
  mx = wred_max(mx);
  sum_t = wred_sumu(sum_t); n_tis = wred_sumu(n_tis);
  if ((threadIdx.x & 63) == 0) {
    atomicAdd(&acc[b].pos_sum, pos_sum);
    atomicAdd(&acc[b].pos_w, pos_w);
    atomicAdd(&acc[b].tpx, tpa);
    atomicAdd(&acc[b].fnx, fna);
    atomicAdd(&acc[b].fpx, fpa);
    atomicMax(&acc[b].max_bce_bits, __float_as_uint(mx));
    atomicAdd(&acc[b].sum_t, sum_t);
    atomicAdd(&acc[b].n_tis, n_tis);
  }
}

// ---------------- K2: per-image histogram scans ----------------
__global__ __launch_bounds__(256) void k_scan(Acc* __restrict__ acc,
                                              const unsigned long long* __restrict__ lov_hist,
                                              const unsigned* __restrict__ neg_hist)
{
  const int b = blockIdx.x;
  const int t = threadIdx.x;
  __shared__ unsigned sA[256], sB[256];
  __shared__ float sf[256];

  const unsigned long long* lh = lov_hist + (size_t)b * NBINS;
  const unsigned* nh = neg_hist + (size_t)b * NBINS;

  const unsigned sum_t = acc[b].sum_t;
  const float p = (float)sum_t;
  const bool has_pos = sum_t > 0;
  const unsigned n_neg_total = (unsigned)PP - sum_t;
  const int CH = NBINS / 256;          // 64 bins per thread
  const float lov_d = LOV_RANGE / (float)NBINS;

  // ---- Lovasz: descending scan (reversed index r = NBINS-1-j) ----
  unsigned tc = 0, tq = 0;
  for (int r = t * CH; r < (t + 1) * CH; ++r) {
    unsigned long long v = lh[NBINS - 1 - r];
    tc += (unsigned)v; tq += (unsigned)(v >> 32);
  }
  sA[t] = tc; sB[t] = tq;
  __syncthreads();
  if (t == 0) {
    unsigned aI = 0, aC = 0;
    for (int i = 0; i < 256; i++) { unsigned ci = sA[i], qi = sB[i]; sA[i] = aI; sB[i] = aC; aI += ci; aC += qi; }
  }
  __syncthreads();

  float local = 0.f;
  if (has_pos) {
    unsigned I = sA[t], C = sB[t];
    float Jprev = 1.f - (p - (float)C) / (p + (float)I - (float)C);   // J(0,0)=0 since p>0
    for (int r = t * CH; r < (t + 1) * CH; ++r) {
      int j = NBINS - 1 - r;
      unsigned long long v = lh[j];
      unsigned c = (unsigned)v, q = (unsigned)(v >> 32);
      if (c) {
        float e = LOV_LO + ((float)j + 0.5f) * lov_d;
        float re = fmaxf(e, 0.f);
        if (n_neg_total > 0) {
          I += c; C += q;
          float Jb = 1.f - (p - (float)C) / (p + (float)I - (float)C);
          local += re * (Jb - Jprev);
          Jprev = Jb;
        } else {
          // n==0: grad_i = jaccard_i = i/p ; sum over run
          double hi = (double)I + (double)c;
          double s = (hi * (hi + 1.0) - (double)I * ((double)I + 1.0)) * 0.5 / (double)p;
          local += re * (float)s;
          I += c;
        }
      }
    }
  }
  sf[t] = local; __syncthreads();
  for (int off = 128; off > 0; off >>= 1) { if (t < off) sf[t] += sf[t + off]; __syncthreads(); }
  float lov = sf[0];
  __syncthreads();

  // ---- OHEM top-k negatives ----
  int n_pos = (int)acc[b].pos_w;      // truncation, as reference astype(int32)
  int n_remain = KALL - n_pos; if (n_remain < 0) n_remain = 0;
  float neg_sum = 0.f; float keptf = 0.f;
  if (n_remain > 0) {
    unsigned tc2 = 0;
    for (int r = t * CH; r < (t + 1) * CH; ++r) tc2 += nh[NBINS - 1 - r];
    sA[t] = tc2; __syncthreads();
    if (t == 0) { unsigned a0 = 0; for (int i = 0; i < 256; i++) { unsigned ci = sA[i]; sA[i] = a0; a0 += ci; } }
    __syncthreads();
    unsigned cum = sA[t];
    const float neg_d = NEG_RANGE / (float)NBINS;
    float ns_local = 0.f; unsigned kept_local = 0;
    for (int r = t * CH; r < (t + 1) * CH; ++r) {
      int j = NBINS - 1 - r;
      unsigned c = nh[j];
      if (c) {
        long long rem = (long long)n_remain - (long long)cum;
        unsigned take = rem <= 0 ? 0u : (rem >= (long long)c ? c : (unsigned)rem);
        if (take) { ns_local += (float)take * (((float)j + 0.5f) * neg_d); kept_local += take; }
        cum += c;
      }
    }
    sf[t] = ns_local; __syncthreads();
    for (int off = 128; off > 0; off >>= 1) { if (t < off) sf[t] += sf[t + off]; __syncthreads(); }
    neg_sum = sf[0]; __syncthreads();
    sf[t] = (float)kept_local; __syncthreads();
    for (int off = 128; off > 0; off >>= 1) { if (t < off) sf[t] += sf[t + off]; __syncthreads(); }
    keptf = sf[0];
  }

  if (t == 0) {
    float cnt = (float)n_pos + keptf;
    float ohem;
    if (cnt > 0.f) ohem = (acc[b].pos_sum + neg_sum) / cnt;
    else ohem = (acc[b].n_tis > 0) ? __uint_as_float(acc[b].max_bce_bits) : acc[b].bce0;
    float tv = (acc[b].tpx + 1e-6f) / (acc[b].tpx + 0.3f * acc[b].fnx + 0.7f * acc[b].fpx + 1e-6f);
    float ft = powf(fmaxf(1.f - tv, 0.f), 1.33f);
    acc[b].lov_i = lov; acc[b].ft_i = ft; acc[b].ohem_i = ohem; acc[b].posb = has_pos ? 1u : 0u;
  }
}

// ---------------- K3: final combine ----------------
__global__ void k_final(const Acc* __restrict__ acc, float* __restrict__ out)
{
  if (threadIdx.x == 0 && blockIdx.x == 0) {
    float os = 0.f, fts = 0.f, lvs = 0.f; int np = 0;
    for (int b = 0; b < BB; b++) {
      os += acc[b].ohem_i;
      if (acc[b].posb) { np++; fts += acc[b].ft_i; lvs += acc[b].lov_i; }
    }
    float denom = (np > 0) ? (float)np : 1.f;
    float r = os / (float)BB;
    if (np > 0) r += fts / denom + 0.2f * (lvs / denom);
    out[0] = r;
  }
}

extern "C" void kernel_launch(void* const* d_in, const int* in_sizes, int n_in,
                              void* d_out, int out_size, void* d_ws, size_t ws_size,
                              hipStream_t stream) {
  const float* logits  = (const float*)d_in[0];
  const int*   targets = (const int*)d_in[1];
  const float* mask    = (const float*)d_in[2];
  float* out = (float*)d_out;

  char* ws = (char*)d_ws;
  Acc* acc = (Acc*)ws;
  const size_t accBytes = BB * sizeof(Acc);          // 1 KB
  unsigned long long* lov_hist = (unsigned long long*)(ws + 1024);
  const size_t lovBytes = (size_t)BB * NBINS * 8;    // 2 MB
  unsigned* neg_hist = (unsigned*)(ws + 1024 + lovBytes);
  const size_t negBytes = (size_t)BB * NBINS * 4;    // 1 MB
  (void)accBytes; (void)in_sizes; (void)n_in; (void)out_size; (void)ws_size;

  hipMemsetAsync(ws, 0, 1024 + lovBytes + negBytes, stream);

  dim3 g1(144, BB, 1);   // 144*256 threads/image, 4 float4 iters each
  k_main<<<g1, 256, 0, stream>>>(logits, targets, mask, acc, lov_hist, neg_hist);
  k_scan<<<BB, 256, 0, stream>>>(acc, lov_hist, neg_hist);
  k_final<<<1, 64, 0, stream>>>(acc, out);
}

// Round 2
// 211.295 us; speedup vs baseline: 5.0296x; 5.0296x over previous
//
#include <hip/hip_runtime.h>
#include <math.h>

#define BB 16
#define PP (768*768)        // 589824
#define NBINS 8192
#define CHUNKS 32           // blocks per image; pixels/block = 18432 < 65536 (u16 pack safe)
#define KALL 176947         // int(P * 0.3)

#define LOV_LO (-17.0f)
#define LOV_RANGE 34.0f
#define NEG_RANGE 17.0f

struct Acc {
  float pos_sum, pos_w, tpx, fnx, fpx, bce0;
  unsigned max_bce_bits, sum_t, n_tis, pad0;
  float lov_i, ft_i, ohem_i; unsigned posb;
  unsigned pad1, pad2;      // 64 bytes total
};

__device__ inline float wred_sum(float v) {
  #pragma unroll
  for (int o = 32; o > 0; o >>= 1) v += __shfl_down(v, o, 64);
  return v;
}
__device__ inline float wred_max(float v) {
  #pragma unroll
  for (int o = 32; o > 0; o >>= 1) v = fmaxf(v, __shfl_down(v, o, 64));
  return v;
}
__device__ inline unsigned wred_sumu(unsigned v) {
  #pragma unroll
  for (int o = 32; o > 0; o >>= 1) v += __shfl_down(v, o, 64);
  return v;
}

// ---------------- K1: fused elementwise pass, LDS-privatized histograms ----------------
__global__ __launch_bounds__(256) void k_main(const float* __restrict__ logits,
                                              const int* __restrict__ targets,
                                              const float* __restrict__ mask,
                                              Acc* __restrict__ acc,
                                              unsigned long long* __restrict__ lov_hist,
                                              unsigned* __restrict__ neg_hist)
{
  const int b = blockIdx.y;
  const int chunk = blockIdx.x;
  __shared__ unsigned lhist[NBINS];   // count | pos<<16
  __shared__ unsigned nhist[NBINS];
  for (int i = threadIdx.x; i < NBINS; i += 256) { lhist[i] = 0u; nhist[i] = 0u; }

  const float4* l4 = (const float4*)(logits + (size_t)b * PP);
  const int4*   t4 = (const int4*)(targets + (size_t)b * PP);
  const float4* m4 = (const float4*)(mask + (size_t)b * PP);
  unsigned long long* lh = lov_hist + (size_t)b * NBINS;
  unsigned*           nh = neg_hist + (size_t)b * NBINS;

  const float lov_scale = (float)NBINS / LOV_RANGE;
  const float neg_scale = (float)NBINS / NEG_RANGE;

  // fallback loss_i[0] (needed when nothing is kept)
  if (chunk == 0 && threadIdx.x == 0) {
    float l = logits[(size_t)b * PP];
    float tf = (float)targets[(size_t)b * PP];
    float m = mask[(size_t)b * PP];
    float ex = expf(-fabsf(l));
    float loss = (fmaxf(l, 0.f) + log1pf(ex) - l * tf) * m;
    acc[b].bce0 = loss;
  }
  __syncthreads();

  float pos_sum = 0.f, pos_w = 0.f, tpa = 0.f, fna = 0.f, fpa = 0.f, mx = 0.f;
  unsigned sum_t = 0, n_tis = 0;

  const int per_chunk4 = (PP / CHUNKS) / 4;          // 4608 float4 per chunk
  const int base4 = chunk * per_chunk4;
  const int iters = per_chunk4 / 256;                // 18

  for (int it = 0; it < iters; ++it) {
    int i = base4 + it * 256 + threadIdx.x;
    float4 lv = l4[i]; int4 tv = t4[i]; float4 mv = m4[i];
    float ls[4] = {lv.x, lv.y, lv.z, lv.w};
    int   ts[4] = {tv.x, tv.y, tv.z, tv.w};
    float ms[4] = {mv.x, mv.y, mv.z, mv.w};
    #pragma unroll
    for (int c = 0; c < 4; ++c) {
      float l = ls[c]; int ti = ts[c]; float tf = (float)ti; float m = ms[c];
      float ex = expf(-fabsf(l));          // shared between softplus & sigmoid
      float lg = log1pf(ex);
      float sp = fmaxf(l, 0.f) + lg;       // softplus(l) = max(l,0)+log1p(exp(-|l|))
      float loss = (sp - l * tf) * m;      // bce * mask
      float posw = tf * m;
      pos_sum += loss * posw;
      pos_w   += posw;
      float pr = ((l >= 0.f) ? 1.f : ex) / (1.f + ex);   // sigmoid(l)
      tpa += pr * tf;
      fna += (1.f - pr) * tf;
      fpa += pr * (1.f - tf);
      sum_t += (unsigned)ti;
      bool tis = (m == 1.0f);
      if (tis) { n_tis++; mx = fmaxf(mx, loss); }
      // lovasz error histogram (LDS, packed count | pos<<16)
      float e = 1.f - l * (2.f * tf - 1.f);
      int bin = (int)((e - LOV_LO) * lov_scale);
      bin = bin < 0 ? 0 : (bin > NBINS - 1 ? NBINS - 1 : bin);
      atomicAdd(&lhist[bin], 1u | ((unsigned)ti << 16));
      // negative-bce histogram (for OHEM top-k; rarely needed but correct)
      if (ti == 0 && tis) {
        int nb = (int)(loss * neg_scale);
        nb = nb < 0 ? 0 : (nb > NBINS - 1 ? NBINS - 1 : nb);
        atomicAdd(&nhist[nb], 1u);
      }
    }
  }

  pos_sum = wred_sum(pos_sum); pos_w = wred_sum(pos_w);
  tpa = wred_sum(tpa); fna = wred_sum(fna); fpa = wred_sum(fpa);
  mx = wred_max(mx);
  sum_t = wred_sumu(sum_t); n_tis = wred_sumu(n_tis);
  if ((threadIdx.x & 63) == 0) {
    atomicAdd(&acc[b].pos_sum, pos_sum);
    atomicAdd(&acc[b].pos_w, pos_w);
    atomicAdd(&acc[b].tpx, tpa);
    atomicAdd(&acc[b].fnx, fna);
    atomicAdd(&acc[b].fpx, fpa);
    atomicMax(&acc[b].max_bce_bits, __float_as_uint(mx));
    atomicAdd(&acc[b].sum_t, sum_t);
    atomicAdd(&acc[b].n_tis, n_tis);
  }

  __syncthreads();
  // flush LDS histograms to global (one atomic per nonzero bin)
  for (int i = threadIdx.x; i < NBINS; i += 256) {
    unsigned v = lhist[i];
    if (v) atomicAdd(lh + i,
        (unsigned long long)(v & 0xFFFFu) | ((unsigned long long)(v >> 16) << 32));
    unsigned nv = nhist[i];
    if (nv) atomicAdd(nh + i, nv);
  }
}

// ---------------- K2: per-image histogram scans ----------------
__global__ __launch_bounds__(256) void k_scan(Acc* __restrict__ acc,
                                              const unsigned long long* __restrict__ lov_hist,
                                              const unsigned* __restrict__ neg_hist)
{
  const int b = blockIdx.x;
  const int t = threadIdx.x;
  __shared__ unsigned sA[256], sB[256];
  __shared__ float sf[256];

  const unsigned long long* lh = lov_hist + (size_t)b * NBINS;
  const unsigned* nh = neg_hist + (size_t)b * NBINS;

  const unsigned sum_t = acc[b].sum_t;
  const float p = (float)sum_t;
  const bool has_pos = sum_t > 0;
  const unsigned n_neg_total = (unsigned)PP - sum_t;
  const int CH = NBINS / 256;          // 32 bins per thread
  const float lov_d = LOV_RANGE / (float)NBINS;

  // ---- Lovasz: descending scan (reversed index r = NBINS-1-j) ----
  unsigned tc = 0, tq = 0;
  for (int r = t * CH; r < (t + 1) * CH; ++r) {
    unsigned long long v = lh[NBINS - 1 - r];
    tc += (unsigned)v; tq += (unsigned)(v >> 32);
  }
  sA[t] = tc; sB[t] = tq;
  __syncthreads();
  if (t == 0) {
    unsigned aI = 0, aC = 0;
    for (int i = 0; i < 256; i++) { unsigned ci = sA[i], qi = sB[i]; sA[i] = aI; sB[i] = aC; aI += ci; aC += qi; }
  }
  __syncthreads();

  float local = 0.f;
  if (has_pos) {
    unsigned I = sA[t], C = sB[t];
    float Jprev = 1.f - (p - (float)C) / (p + (float)I - (float)C);   // J(0,0)=0 since p>0
    for (int r = t * CH; r < (t + 1) * CH; ++r) {
      int j = NBINS - 1 - r;
      unsigned long long v = lh[j];
      unsigned c = (unsigned)v, q = (unsigned)(v >> 32);
      if (c) {
        float e = LOV_LO + ((float)j + 0.5f) * lov_d;
        float re = fmaxf(e, 0.f);
        if (n_neg_total > 0) {
          I += c; C += q;
          float Jb = 1.f - (p - (float)C) / (p + (float)I - (float)C);
          local += re * (Jb - Jprev);
          Jprev = Jb;
        } else {
          // n==0: grad_i = jaccard_i = i/p ; sum over run
          double hi = (double)I + (double)c;
          double s = (hi * (hi + 1.0) - (double)I * ((double)I + 1.0)) * 0.5 / (double)p;
          local += re * (float)s;
          I += c;
        }
      }
    }
  }
  sf[t] = local; __syncthreads();
  for (int off = 128; off > 0; off >>= 1) { if (t < off) sf[t] += sf[t + off]; __syncthreads(); }
  float lov = sf[0];
  __syncthreads();

  // ---- OHEM top-k negatives ----
  int n_pos = (int)acc[b].pos_w;      // truncation, as reference astype(int32)
  int n_remain = KALL - n_pos; if (n_remain < 0) n_remain = 0;
  float neg_sum = 0.f; float keptf = 0.f;
  if (n_remain > 0) {
    unsigned tc2 = 0;
    for (int r = t * CH; r < (t + 1) * CH; ++r) tc2 += nh[NBINS - 1 - r];
    sA[t] = tc2; __syncthreads();
    if (t == 0) { unsigned a0 = 0; for (int i = 0; i < 256; i++) { unsigned ci = sA[i]; sA[i] = a0; a0 += ci; } }
    __syncthreads();
    unsigned cum = sA[t];
    const float neg_d = NEG_RANGE / (float)NBINS;
    float ns_local = 0.f; unsigned kept_local = 0;
    for (int r = t * CH; r < (t + 1) * CH; ++r) {
      int j = NBINS - 1 - r;
      unsigned c = nh[j];
      if (c) {
        long long rem = (long long)n_remain - (long long)cum;
        unsigned take = rem <= 0 ? 0u : (rem >= (long long)c ? c : (unsigned)rem);
        if (take) { ns_local += (float)take * (((float)j + 0.5f) * neg_d); kept_local += take; }
        cum += c;
      }
    }
    sf[t] = ns_local; __syncthreads();
    for (int off = 128; off > 0; off >>= 1) { if (t < off) sf[t] += sf[t + off]; __syncthreads(); }
    neg_sum = sf[0]; __syncthreads();
    sf[t] = (float)kept_local; __syncthreads();
    for (int off = 128; off > 0; off >>= 1) { if (t < off) sf[t] += sf[t + off]; __syncthreads(); }
    keptf = sf[0];
  }

  if (t == 0) {
    float cnt = (float)n_pos + keptf;
    float ohem;
    if (cnt > 0.f) ohem = (acc[b].pos_sum + neg_sum) / cnt;
    else ohem = (acc[b].n_tis > 0) ? __uint_as_float(acc[b].max_bce_bits) : acc[b].bce0;
    float tv = (acc[b].tpx + 1e-6f) / (acc[b].tpx + 0.3f * acc[b].fnx + 0.7f * acc[b].fpx + 1e-6f);
    float ft = powf(fmaxf(1.f - tv, 0.f), 1.33f);
    acc[b].lov_i = lov; acc[b].ft_i = ft; acc[b].ohem_i = ohem; acc[b].posb = has_pos ? 1u : 0u;
  }
}

// ---------------- K3: final combine ----------------
__global__ void k_final(const Acc* __restrict__ acc, float* __restrict__ out)
{
  if (threadIdx.x == 0 && blockIdx.x == 0) {
    float os = 0.f, fts = 0.f, lvs = 0.f; int np = 0;
    for (int b = 0; b < BB; b++) {
      os += acc[b].ohem_i;
      if (acc[b].posb) { np++; fts += acc[b].ft_i; lvs += acc[b].lov_i; }
    }
    float denom = (np > 0) ? (float)np : 1.f;
    float r = os / (float)BB;
    if (np > 0) r += fts / denom + 0.2f * (lvs / denom);
    out[0] = r;
  }
}

extern "C" void kernel_launch(void* const* d_in, const int* in_sizes, int n_in,
                              void* d_out, int out_size, void* d_ws, size_t ws_size,
                              hipStream_t stream) {
  const float* logits  = (const float*)d_in[0];
  const int*   targets = (const int*)d_in[1];
  const float* mask    = (const float*)d_in[2];
  float* out = (float*)d_out;

  char* ws = (char*)d_ws;
  Acc* acc = (Acc*)ws;
  unsigned long long* lov_hist = (unsigned long long*)(ws + 1024);
  const size_t lovBytes = (size_t)BB * NBINS * 8;    // 1 MB
  unsigned* neg_hist = (unsigned*)(ws + 1024 + lovBytes);
  const size_t negBytes = (size_t)BB * NBINS * 4;    // 0.5 MB
  (void)in_sizes; (void)n_in; (void)out_size; (void)ws_size;

  hipMemsetAsync(ws, 0, 1024 + lovBytes + negBytes, stream);

  dim3 g1(CHUNKS, BB, 1);   // 512 blocks, 64KB LDS each -> 2 blocks/CU
  k_main<<<g1, 256, 0, stream>>>(logits, targets, mask, acc, lov_hist, neg_hist);
  k_scan<<<BB, 256, 0, stream>>>(acc, lov_hist, neg_hist);
  k_final<<<1, 64, 0, stream>>>(acc, out);
}

// Round 3
// 191.890 us; speedup vs baseline: 5.5382x; 1.1011x over previous
//
#include <hip/hip_runtime.h>
#include <math.h>

#define BB 16
#define PP (768*768)        // 589824
#define NBINS 4096
#define CHUNKS 64           // blocks per image; pixels/block = 9216
#define KALL 176947         // int(P * 0.3)

#define LOV_LO (-17.0f)
#define LOV_RANGE 34.0f

typedef unsigned long long u64;

struct Acc {
  float pos_sum, pos_w, tpx, sprx, bce0;
  unsigned max_bce_bits, sum_t, n_tis;
  float lov_i, ft_i, ohem_i; unsigned posb;
  unsigned pad[4];          // 64 bytes
};

__device__ inline float wred_sum(float v) {
  #pragma unroll
  for (int o = 32; o > 0; o >>= 1) v += __shfl_down(v, o, 64);
  return v;
}
__device__ inline float wred_max(float v) {
  #pragma unroll
  for (int o = 32; o > 0; o >>= 1) v = fmaxf(v, __shfl_down(v, o, 64));
  return v;
}
__device__ inline unsigned wred_sumu(unsigned v) {
  #pragma unroll
  for (int o = 32; o > 0; o >>= 1) v += __shfl_down(v, o, 64);
  return v;
}

// ---------------- K1: fused elementwise pass, single merged LDS histogram ----------------
// hist bin keyed by lovasz error e = 1 - l*(2t-1); packed u64:
//   count [0..19] | pos [20..39] | negtis [40..59]
__global__ __launch_bounds__(256) void k_main(const float* __restrict__ logits,
                                              const int* __restrict__ targets,
                                              const float* __restrict__ mask,
                                              Acc* __restrict__ acc,
                                              u64* __restrict__ ghist)
{
  const int b = blockIdx.y;
  const int chunk = blockIdx.x;
  __shared__ u64 hist[NBINS];   // 32 KB
  for (int i = threadIdx.x; i < NBINS; i += 256) hist[i] = 0ull;

  const float4* l4 = (const float4*)(logits + (size_t)b * PP);
  const int4*   t4 = (const int4*)(targets + (size_t)b * PP);
  const float4* m4 = (const float4*)(mask + (size_t)b * PP);
  u64* gh = ghist + (size_t)b * NBINS;

  const float lov_scale = (float)NBINS / LOV_RANGE;

  // fallback loss_i[0]
  if (chunk == 0 && threadIdx.x == 0) {
    float l = logits[(size_t)b * PP];
    float tf = (float)targets[(size_t)b * PP];
    float m = mask[(size_t)b * PP];
    float ex = __expf(-fabsf(l));
    acc[b].bce0 = (fmaxf(l, 0.f) + __logf(1.f + ex) - l * tf) * m;
  }
  __syncthreads();

  float pos_sum = 0.f, pos_w = 0.f, tpa = 0.f, spra = 0.f, mx = 0.f;
  unsigned sum_t = 0, n_tis = 0;

  const int per_chunk4 = (PP / CHUNKS) / 4;          // 2304
  const int base4 = chunk * per_chunk4;
  const int iters = per_chunk4 / 256;                // 9

  for (int it = 0; it < iters; ++it) {
    int i = base4 + it * 256 + threadIdx.x;
    float4 lv = l4[i]; int4 tv = t4[i]; float4 mv = m4[i];
    float ls[4] = {lv.x, lv.y, lv.z, lv.w};
    int   ts[4] = {tv.x, tv.y, tv.z, tv.w};
    float ms[4] = {mv.x, mv.y, mv.z, mv.w};
    #pragma unroll
    for (int c = 0; c < 4; ++c) {
      float l = ls[c]; int ti = ts[c]; float tf = (float)ti; float m = ms[c];
      float ex = __expf(-fabsf(l));                    // e^{-|l|}
      float lg = __logf(1.f + ex);                     // log1p via hw log (1+ex in (1,2])
      float loss = (fmaxf(l, 0.f) + lg - l * tf) * m;  // bce * mask
      float posw = tf * m;
      pos_sum = fmaf(loss, posw, pos_sum);
      pos_w  += posw;
      float pr = ((l >= 0.f) ? 1.f : ex) * __builtin_amdgcn_rcpf(1.f + ex);  // sigmoid
      spra += pr;
      tpa = fmaf(pr, tf, tpa);
      sum_t += (unsigned)ti;
      bool tis = (m == 1.0f);
      if (tis) { n_tis++; mx = fmaxf(mx, loss); }
      float s = fmaf(2.f, tf, -1.f);
      float e = fmaf(-l, s, 1.f);                      // lovasz error
      int bin = (int)((e - LOV_LO) * lov_scale);
      bin = bin < 0 ? 0 : (bin > NBINS - 1 ? NBINS - 1 : bin);
      u64 val = 1ull | ((u64)(unsigned)ti << 20) |
                ((u64)(unsigned)((ti == 0) & tis) << 40);
      atomicAdd(&hist[bin], val);
    }
  }

  pos_sum = wred_sum(pos_sum); pos_w = wred_sum(pos_w);
  tpa = wred_sum(tpa); spra = wred_sum(spra);
  mx = wred_max(mx);
  sum_t = wred_sumu(sum_t); n_tis = wred_sumu(n_tis);
  if ((threadIdx.x & 63) == 0) {
    atomicAdd(&acc[b].pos_sum, pos_sum);
    atomicAdd(&acc[b].pos_w, pos_w);
    atomicAdd(&acc[b].tpx, tpa);
    atomicAdd(&acc[b].sprx, spra);
    atomicMax(&acc[b].max_bce_bits, __float_as_uint(mx));
    atomicAdd(&acc[b].sum_t, sum_t);
    atomicAdd(&acc[b].n_tis, n_tis);
  }

  __syncthreads();
  for (int i = threadIdx.x; i < NBINS; i += 256) {
    u64 v = hist[i];
    if (v) atomicAdd(gh + i, v);
  }
}

// ---------------- K2: per-image single descending walk (lovasz + OHEM) ----------------
__global__ __launch_bounds__(256) void k_scan(Acc* __restrict__ acc,
                                              const u64* __restrict__ ghist)
{
  const int b = blockIdx.x;
  const int t = threadIdx.x;
  __shared__ unsigned sA[256], sB[256], sC[256];
  __shared__ float sf[256], sg[256];
  __shared__ unsigned ng_total_sh;

  const u64* gh = ghist + (size_t)b * NBINS;

  const unsigned sum_t = acc[b].sum_t;
  const float p = (float)sum_t;
  const bool has_pos = sum_t > 0;
  const unsigned n_neg_total = (unsigned)PP - sum_t;
  const int CH = NBINS / 256;          // 16 bins per thread
  const float lov_d = LOV_RANGE / (float)NBINS;

  int n_pos = (int)acc[b].pos_w;       // truncation like astype(int32)
  int n_remain = KALL - n_pos; if (n_remain < 0) n_remain = 0;

  // per-thread chunk totals (reversed order: r = NBINS-1-j descending e)
  u64 loc[16];
  unsigned tc = 0, tq = 0, tn = 0;
  #pragma unroll
  for (int k = 0; k < 16; ++k) {
    u64 v = gh[NBINS - 1 - (t * CH + k)];
    loc[k] = v;
    tc += (unsigned)(v & 0xFFFFFu);
    tq += (unsigned)((v >> 20) & 0xFFFFFu);
    tn += (unsigned)((v >> 40) & 0xFFFFFu);
  }
  sA[t] = tc; sB[t] = tq; sC[t] = tn;
  __syncthreads();
  if (t == 0) {
    unsigned aI = 0, aC = 0, aN = 0;
    for (int i = 0; i < 256; i++) {
      unsigned ci = sA[i], qi = sB[i], ni = sC[i];
      sA[i] = aI; sB[i] = aC; sC[i] = aN;
      aI += ci; aC += qi; aN += ni;
    }
    ng_total_sh = aN;
  }
  __syncthreads();

  float lov_local = 0.f, ns_local = 0.f;
  {
    unsigned I = sA[t], C = sB[t], NG = sC[t];
    float Jprev = has_pos ? (1.f - (p - (float)C) / (p + (float)I - (float)C)) : 0.f;
    #pragma unroll 4
    for (int k = 0; k < 16; ++k) {
      int j = NBINS - 1 - (t * CH + k);
      u64 v = loc[k];
      unsigned c = (unsigned)(v & 0xFFFFFu);
      if (c) {
        unsigned q = (unsigned)((v >> 20) & 0xFFFFFu);
        unsigned ng = (unsigned)((v >> 40) & 0xFFFFFu);
        float e = LOV_LO + ((float)j + 0.5f) * lov_d;
        if (has_pos) {
          float re = fmaxf(e, 0.f);
          if (n_neg_total > 0) {
            I += c; C += q;
            float Jb = 1.f - (p - (float)C) / (p + (float)I - (float)C);
            lov_local += re * (Jb - Jprev);
            Jprev = Jb;
          } else {
            double hi = (double)I + (double)c;
            double s = (hi * (hi + 1.0) - (double)I * ((double)I + 1.0)) * 0.5 / (double)p;
            lov_local += re * (float)s;
            I += c;
          }
        }
        if (n_remain > 0 && ng) {
          long long rem = (long long)n_remain - (long long)NG;
          unsigned take = rem <= 0 ? 0u : (rem >= (long long)ng ? ng : (unsigned)rem);
          if (take) {
            float l = e - 1.f;                         // negatives: e = 1 + l
            float nloss = fmaxf(l, 0.f) + __logf(1.f + __expf(-fabsf(l)));
            ns_local += (float)take * nloss;
          }
          NG += ng;
        }
      }
    }
  }
  sf[t] = lov_local; sg[t] = ns_local; __syncthreads();
  for (int off = 128; off > 0; off >>= 1) {
    if (t < off) { sf[t] += sf[t + off]; sg[t] += sg[t + off]; }
    __syncthreads();
  }

  if (t == 0) {
    float lov = sf[0];
    float neg_sum = sg[0];
    unsigned kept = (n_remain > 0)
        ? ((unsigned)n_remain < ng_total_sh ? (unsigned)n_remain : ng_total_sh) : 0u;
    float cnt = (float)n_pos + (float)kept;
    float ohem;
    if (cnt > 0.f) ohem = (acc[b].pos_sum + neg_sum) / cnt;
    else ohem = (acc[b].n_tis > 0) ? __uint_as_float(acc[b].max_bce_bits) : acc[b].bce0;
    float tp = acc[b].tpx;
    float fn = p - tp;
    float fp = acc[b].sprx - tp;
    float tv = (tp + 1e-6f) / (tp + 0.3f * fn + 0.7f * fp + 1e-6f);
    float ft = powf(fmaxf(1.f - tv, 0.f), 1.33f);
    acc[b].lov_i = lov; acc[b].ft_i = ft; acc[b].ohem_i = ohem;
    acc[b].posb = has_pos ? 1u : 0u;
  }
}

// ---------------- K3: final combine ----------------
__global__ void k_final(const Acc* __restrict__ acc, float* __restrict__ out)
{
  if (threadIdx.x == 0 && blockIdx.x == 0) {
    float os = 0.f, fts = 0.f, lvs = 0.f; int np = 0;
    for (int b = 0; b < BB; b++) {
      os += acc[b].ohem_i;
      if (acc[b].posb) { np++; fts += acc[b].ft_i; lvs += acc[b].lov_i; }
    }
    float denom = (np > 0) ? (float)np : 1.f;
    float r = os / (float)BB;
    if (np > 0) r += fts / denom + 0.2f * (lvs / denom);
    out[0] = r;
  }
}

extern "C" void kernel_launch(void* const* d_in, const int* in_sizes, int n_in,
                              void* d_out, int out_size, void* d_ws, size_t ws_size,
                              hipStream_t stream) {
  const float* logits  = (const float*)d_in[0];
  const int*   targets = (const int*)d_in[1];
  const float* mask    = (const float*)d_in[2];
  float* out = (float*)d_out;

  char* ws = (char*)d_ws;
  Acc* acc = (Acc*)ws;
  u64* ghist = (u64*)(ws + 1024);
  const size_t histBytes = (size_t)BB * NBINS * 8;   // 512 KB
  (void)in_sizes; (void)n_in; (void)out_size; (void)ws_size;

  hipMemsetAsync(ws, 0, 1024 + histBytes, stream);

  dim3 g1(CHUNKS, BB, 1);   // 1024 blocks, 32KB LDS each -> 4 blocks/CU resident
  k_main<<<g1, 256, 0, stream>>>(logits, targets, mask, acc, ghist);
  k_scan<<<BB, 256, 0, stream>>>(acc, ghist);
  k_final<<<1, 64, 0, stream>>>(acc, out);
}